// Round 2
// baseline (5035.370 us; speedup 1.0000x reference)
//
#include <hip/hip_runtime.h>

#define NN 100000
#define EE 1000000
#define ET 1100000           // EE + NN self-loops
#define NFEAT 512
#define NHID 32
#define HEADS 8
#define F1 256               // HEADS*NHID
#define NCLASS 40
#define SLOPE 0.2f

typedef __bf16 bf16x8 __attribute__((ext_vector_type(8)));
typedef float f32x4 __attribute__((ext_vector_type(4)));

union BF8 { unsigned short s[8]; bf16x8 v; uint4 u; };

__device__ __forceinline__ float bf2f(unsigned short u) {
    return __uint_as_float(((unsigned)u) << 16);
}
__device__ __forceinline__ unsigned short f2bf(float f) {
    unsigned x = __float_as_uint(f);
    unsigned r = (x + 0x7fffu + ((x >> 16) & 1u)) >> 16;
    return (unsigned short)r;
}
__device__ __forceinline__ void cvt2(float f, unsigned short& hi, unsigned short& lo) {
    hi = f2bf(f);
    lo = f2bf(f - bf2f(hi));
}
// order-preserving float->uint for atomicMax; init 0 is below any real encoding
__device__ __forceinline__ unsigned encf(float f) {
    unsigned u = __float_as_uint(f);
    return (u & 0x80000000u) ? ~u : (u | 0x80000000u);
}
__device__ __forceinline__ float decf(unsigned u) {
    return __uint_as_float((u & 0x80000000u) ? (u ^ 0x80000000u) : ~u);
}
__device__ __forceinline__ float lrelu(float x) { return x > 0.f ? x : SLOPE * x; }

// ---------------- edge-index canonicalization (int32 vs int64 layout) --------
__global__ void detect_i64(const int* __restrict__ ei, int* __restrict__ flag) {
    int i = blockIdx.x * 256 + threadIdx.x;
    if (i < 4096) {
        // int64 data: odd int32 words are high words of values < 2^17 -> all 0.
        if (ei[2 * i + 1] != 0) atomicOr(flag, 1);
    }
}
__global__ void canon_edges(const int* __restrict__ ei, const int* __restrict__ flag,
                            int* __restrict__ srcC, int* __restrict__ dstC) {
    int e = blockIdx.x * 256 + threadIdx.x;
    if (e >= EE) return;
    if (*flag) {               // int32 layout
        srcC[e] = ei[e];
        dstC[e] = ei[EE + e];
    } else {                   // int64 little-endian layout
        srcC[e] = ei[2 * e];
        dstC[e] = ei[2 * EE + 2 * e];
    }
}

// ---------------- W1 prep: fp32 [512,256] -> hi/lo bf16 transposed [256,512] --
__global__ void prep_w1(const float* __restrict__ w1,
                        unsigned short* __restrict__ w1th,
                        unsigned short* __restrict__ w1tl) {
    int t = blockIdx.x * 256 + threadIdx.x;
    if (t < NFEAT * F1) {
        int k = t / F1, n = t % F1;
        unsigned short hi, lo;
        cvt2(w1[t], hi, lo);
        w1th[n * NFEAT + k] = hi;
        w1tl[n * NFEAT + k] = lo;
    }
}

// ---------------- GEMM1: h[N,256] = x[N,512] @ W1, split-bf16 MFMA -----------
// wave computes 16x64; block = 4 waves stacked in M => 64x64 per block
__global__ __launch_bounds__(256) void gemm1_kernel(
    const float* __restrict__ x, const unsigned short* __restrict__ w1th,
    const unsigned short* __restrict__ w1tl, float* __restrict__ h) {
    int tid = threadIdx.x;
    int wave = tid >> 6, lane = tid & 63;
    int quad = lane >> 4, r = lane & 15;
    int mBase = blockIdx.x * 64 + wave * 16;
    int nBase = blockIdx.y * 64;
    long arow = mBase + r; if (arow > NN - 1) arow = NN - 1;
    const float4* aptr = (const float4*)(x + arow * NFEAT) + quad * 2;
    const uint4* bh0 = (const uint4*)(w1th + (long)(nBase + 0 * 16 + r) * NFEAT) + quad;
    const uint4* bh1 = (const uint4*)(w1th + (long)(nBase + 1 * 16 + r) * NFEAT) + quad;
    const uint4* bh2 = (const uint4*)(w1th + (long)(nBase + 2 * 16 + r) * NFEAT) + quad;
    const uint4* bh3 = (const uint4*)(w1th + (long)(nBase + 3 * 16 + r) * NFEAT) + quad;
    const uint4* bl0 = (const uint4*)(w1tl + (long)(nBase + 0 * 16 + r) * NFEAT) + quad;
    const uint4* bl1 = (const uint4*)(w1tl + (long)(nBase + 1 * 16 + r) * NFEAT) + quad;
    const uint4* bl2 = (const uint4*)(w1tl + (long)(nBase + 2 * 16 + r) * NFEAT) + quad;
    const uint4* bl3 = (const uint4*)(w1tl + (long)(nBase + 3 * 16 + r) * NFEAT) + quad;

    f32x4 acc0 = {0.f,0.f,0.f,0.f}, acc1 = {0.f,0.f,0.f,0.f};
    f32x4 acc2 = {0.f,0.f,0.f,0.f}, acc3 = {0.f,0.f,0.f,0.f};

    #pragma unroll
    for (int k = 0; k < NFEAT / 32; k++) {
        float4 fa0 = aptr[k * 8];
        float4 fa1 = aptr[k * 8 + 1];
        float fa[8] = {fa0.x, fa0.y, fa0.z, fa0.w, fa1.x, fa1.y, fa1.z, fa1.w};
        BF8 ah, al;
        #pragma unroll
        for (int j = 0; j < 8; j++) {
            unsigned short hh, ll;
            cvt2(fa[j], hh, ll);
            ah.s[j] = hh; al.s[j] = ll;
        }
        BF8 h0, h1_, h2_, h3, l0, l1, l2, l3;
        h0.u = bh0[k * 4]; h1_.u = bh1[k * 4]; h2_.u = bh2[k * 4]; h3.u = bh3[k * 4];
        l0.u = bl0[k * 4]; l1.u = bl1[k * 4]; l2.u = bl2[k * 4]; l3.u = bl3[k * 4];
        acc0 = __builtin_amdgcn_mfma_f32_16x16x32_bf16(ah.v, h0.v, acc0, 0, 0, 0);
        acc0 = __builtin_amdgcn_mfma_f32_16x16x32_bf16(al.v, h0.v, acc0, 0, 0, 0);
        acc0 = __builtin_amdgcn_mfma_f32_16x16x32_bf16(ah.v, l0.v, acc0, 0, 0, 0);
        acc1 = __builtin_amdgcn_mfma_f32_16x16x32_bf16(ah.v, h1_.v, acc1, 0, 0, 0);
        acc1 = __builtin_amdgcn_mfma_f32_16x16x32_bf16(al.v, h1_.v, acc1, 0, 0, 0);
        acc1 = __builtin_amdgcn_mfma_f32_16x16x32_bf16(ah.v, l1.v, acc1, 0, 0, 0);
        acc2 = __builtin_amdgcn_mfma_f32_16x16x32_bf16(ah.v, h2_.v, acc2, 0, 0, 0);
        acc2 = __builtin_amdgcn_mfma_f32_16x16x32_bf16(al.v, h2_.v, acc2, 0, 0, 0);
        acc2 = __builtin_amdgcn_mfma_f32_16x16x32_bf16(ah.v, l2.v, acc2, 0, 0, 0);
        acc3 = __builtin_amdgcn_mfma_f32_16x16x32_bf16(ah.v, h3.v, acc3, 0, 0, 0);
        acc3 = __builtin_amdgcn_mfma_f32_16x16x32_bf16(al.v, h3.v, acc3, 0, 0, 0);
        acc3 = __builtin_amdgcn_mfma_f32_16x16x32_bf16(ah.v, l3.v, acc3, 0, 0, 0);
    }
    #pragma unroll
    for (int i = 0; i < 4; i++) {
        int m = mBase + quad * 4 + i;
        if (m < NN) {
            float* hp = h + (long)m * F1 + nBase + r;
            hp[0]  = acc0[i];
            hp[16] = acc1[i];
            hp[32] = acc2[i];
            hp[48] = acc3[i];
        }
    }
}

// ---------------- e_src/e_dst layer1 + init m1/den1 ----------------
__global__ __launch_bounds__(256) void escore1_kernel(
    const float* __restrict__ h, const float* __restrict__ a_src,
    const float* __restrict__ a_dst, float* __restrict__ es,
    float* __restrict__ ed, unsigned* __restrict__ m1, float* __restrict__ den1) {
    __shared__ float As[F1], Ad[F1];
    int tid = threadIdx.x;
    As[tid] = a_src[tid];
    Ad[tid] = a_dst[tid];
    __syncthreads();
    int t = blockIdx.x * 256 + tid;
    if (t >= NN * HEADS) return;
    int n = t >> 3, hd = t & 7;
    const float* hp = h + (long)n * F1 + hd * NHID;
    float s = 0.f, d = 0.f;
    #pragma unroll
    for (int c = 0; c < NHID; c++) {
        float v = hp[c];
        s += v * As[hd * NHID + c];
        d += v * Ad[hd * NHID + c];
    }
    es[t] = s; ed[t] = d; m1[t] = 0u; den1[t] = 0.f;
}

// ---------------- edge pass 1: max ----------------
__global__ void epass1_max(const int* __restrict__ srcC, const int* __restrict__ dstC,
                           const float* __restrict__ es, const float* __restrict__ ed,
                           unsigned* __restrict__ m1) {
    long t = (long)blockIdx.x * 256 + threadIdx.x;
    if (t >= (long)ET * HEADS) return;
    int e = (int)(t >> 3), hd = (int)(t & 7);
    int s, d;
    if (e < EE) { s = srcC[e]; d = dstC[e]; } else { s = d = e - EE; }
    float el = lrelu(es[s * 8 + hd] + ed[d * 8 + hd]);
    atomicMax(m1 + d * 8 + hd, encf(el));
}

// ---------------- edge pass 1: denom ----------------
__global__ void epass1_sum(const int* __restrict__ srcC, const int* __restrict__ dstC,
                           const float* __restrict__ es, const float* __restrict__ ed,
                           const unsigned* __restrict__ m1, float* __restrict__ den1) {
    long t = (long)blockIdx.x * 256 + threadIdx.x;
    if (t >= (long)ET * HEADS) return;
    int e = (int)(t >> 3), hd = (int)(t & 7);
    int s, d;
    if (e < EE) { s = srcC[e]; d = dstC[e]; } else { s = d = e - EE; }
    float el = lrelu(es[s * 8 + hd] + ed[d * 8 + hd]);
    float ex = __expf(el - decf(m1[d * 8 + hd]));
    atomicAdd(den1 + d * 8 + hd, ex);
}

// ---------------- edge pass 1: weighted scatter (wave per edge) ----------------
__global__ __launch_bounds__(256) void epass1_scatter(
    const int* __restrict__ srcC, const int* __restrict__ dstC,
    const float* __restrict__ es, const float* __restrict__ ed,
    const unsigned* __restrict__ m1, const float* __restrict__ den1,
    const float* __restrict__ h, float* __restrict__ out1) {
    int wave = threadIdx.x >> 6, lane = threadIdx.x & 63;
    long e = (long)blockIdx.x * 4 + wave;
    if (e >= ET) return;
    int s, d;
    if (e < EE) { s = srcC[e]; d = dstC[e]; } else { s = d = (int)(e - EE); }
    int hd = lane >> 3;
    float el = lrelu(es[s * 8 + hd] + ed[d * 8 + hd]);
    float alpha = __expf(el - decf(m1[d * 8 + hd])) / den1[d * 8 + hd];
    float4 v = ((const float4*)(h + (long)s * F1))[lane];
    float* op = out1 + (long)d * F1 + lane * 4;
    atomicAdd(op + 0, alpha * v.x);
    atomicAdd(op + 1, alpha * v.y);
    atomicAdd(op + 2, alpha * v.z);
    atomicAdd(op + 3, alpha * v.w);
}

// ---------------- bias + ELU -> h1 fp32 (ws, in place) + fp32 out region -----
__global__ void bias_elu1(float* __restrict__ out1, const float* __restrict__ b1,
                          float* __restrict__ h1_out) {
    long t = (long)blockIdx.x * 256 + threadIdx.x;
    if (t >= (long)NN * F1) return;
    int c = (int)(t & 255);
    float v = out1[t] + b1[c];
    float r = v > 0.f ? v : expm1f(v);
    out1[t] = r;
    h1_out[t] = r;
}

// ---------------- GEMM2: h2[N,40] = h1[N,256] @ W2 (fp32, W2 in LDS) ----------
__global__ __launch_bounds__(256) void gemm2_kernel(const float* __restrict__ h1,
                                                    const float* __restrict__ w2,
                                                    float* __restrict__ h2) {
    __shared__ float Ws[F1 * NCLASS];
    for (int i = threadIdx.x; i < F1 * NCLASS; i += 256) Ws[i] = w2[i];
    __syncthreads();
    long t = (long)blockIdx.x * 256 + threadIdx.x;
    if (t >= (long)NN * NCLASS) return;
    int n = (int)(t / NCLASS);
    int c = (int)(t - (long)n * NCLASS);
    const float* hp = h1 + (long)n * F1;
    float acc = 0.f;
    #pragma unroll 8
    for (int k = 0; k < F1; k++) acc += hp[k] * Ws[k * NCLASS + c];
    h2[t] = acc;
}

// ---------------- e_src/e_dst layer2 + init m2/den2 ----------------
__global__ void escore2_kernel(const float* __restrict__ h2,
                               const float* __restrict__ a_src2,
                               const float* __restrict__ a_dst2,
                               float* __restrict__ e2s, float* __restrict__ e2d,
                               unsigned* __restrict__ m2, float* __restrict__ den2) {
    __shared__ float As[NCLASS], Ad[NCLASS];
    if (threadIdx.x < NCLASS) {
        As[threadIdx.x] = a_src2[threadIdx.x];
        Ad[threadIdx.x] = a_dst2[threadIdx.x];
    }
    __syncthreads();
    int n = blockIdx.x * 256 + threadIdx.x;
    if (n >= NN) return;
    const float* hp = h2 + (long)n * NCLASS;
    float s = 0.f, d = 0.f;
    #pragma unroll
    for (int c = 0; c < NCLASS; c++) {
        float v = hp[c];
        s += v * As[c];
        d += v * Ad[c];
    }
    e2s[n] = s; e2d[n] = d; m2[n] = 0u; den2[n] = 0.f;
}

__global__ void epass2_max(const int* __restrict__ srcC, const int* __restrict__ dstC,
                           const float* __restrict__ e2s, const float* __restrict__ e2d,
                           unsigned* __restrict__ m2) {
    long t = (long)blockIdx.x * 256 + threadIdx.x;
    if (t >= ET) return;
    int e = (int)t, s, d;
    if (e < EE) { s = srcC[e]; d = dstC[e]; } else { s = d = e - EE; }
    float el = lrelu(e2s[s] + e2d[d]);
    atomicMax(m2 + d, encf(el));
}

__global__ void epass2_sum(const int* __restrict__ srcC, const int* __restrict__ dstC,
                           const float* __restrict__ e2s, const float* __restrict__ e2d,
                           const unsigned* __restrict__ m2, float* __restrict__ den2) {
    long t = (long)blockIdx.x * 256 + threadIdx.x;
    if (t >= ET) return;
    int e = (int)t, s, d;
    if (e < EE) { s = srcC[e]; d = dstC[e]; } else { s = d = e - EE; }
    float el = lrelu(e2s[s] + e2d[d]);
    atomicAdd(den2 + d, __expf(el - decf(m2[d])));
}

__global__ __launch_bounds__(256) void epass2_scatter(
    const int* __restrict__ srcC, const int* __restrict__ dstC,
    const float* __restrict__ e2s, const float* __restrict__ e2d,
    const unsigned* __restrict__ m2, const float* __restrict__ den2,
    const float* __restrict__ h2, float* __restrict__ out2) {
    int wave = threadIdx.x >> 6, lane = threadIdx.x & 63;
    long e = (long)blockIdx.x * 4 + wave;
    if (e >= ET || lane >= NCLASS) return;
    int s, d;
    if (e < EE) { s = srcC[e]; d = dstC[e]; } else { s = d = (int)(e - EE); }
    float el = lrelu(e2s[s] + e2d[d]);
    float alpha = __expf(el - decf(m2[d])) / den2[d];
    atomicAdd(out2 + (long)d * NCLASS + lane, alpha * h2[(long)s * NCLASS + lane]);
}

// ---------------- bias + log_softmax -> fp32 out0 ----------------
__global__ void logsm_kernel(const float* __restrict__ out2,
                             const float* __restrict__ b2,
                             float* __restrict__ out0) {
    int n = blockIdx.x * 256 + threadIdx.x;
    if (n >= NN) return;
    float v[NCLASS];
    float mx = -1e30f;
    #pragma unroll
    for (int c = 0; c < NCLASS; c++) {
        v[c] = out2[(long)n * NCLASS + c] + b2[c];
        mx = fmaxf(mx, v[c]);
    }
    float sum = 0.f;
    #pragma unroll
    for (int c = 0; c < NCLASS; c++) sum += __expf(v[c] - mx);
    float ls = mx + logf(sum);
    #pragma unroll
    for (int c = 0; c < NCLASS; c++) out0[(long)n * NCLASS + c] = v[c] - ls;
}

extern "C" void kernel_launch(void* const* d_in, const int* in_sizes, int n_in,
                              void* d_out, int out_size, void* d_ws, size_t ws_size,
                              hipStream_t stream) {
    const float* x   = (const float*)d_in[0];
    const int* ei    = (const int*)d_in[1];
    const float* W1  = (const float*)d_in[2];
    const float* as1 = (const float*)d_in[3];
    const float* ad1 = (const float*)d_in[4];
    const float* b1  = (const float*)d_in[5];
    const float* W2  = (const float*)d_in[6];
    const float* as2 = (const float*)d_in[7];
    const float* ad2 = (const float*)d_in[8];
    const float* b2  = (const float*)d_in[9];

    float* out0 = (float*)d_out;                   // [N,40] log_softmax
    float* h1o  = out0 + (long)NN * NCLASS;        // [N,256] h1

    // workspace layout
    float* h    = (float*)d_ws;                    // N*F1 fp32
    float* out1 = h + (long)NN * F1;               // N*F1 fp32
    unsigned short* w1th = (unsigned short*)(out1 + (long)NN * F1);  // 512*256 bf16
    unsigned short* w1tl = w1th + NFEAT * F1;
    float* es1  = (float*)(w1tl + NFEAT * F1);     // N*8
    float* ed1  = es1 + NN * HEADS;
    unsigned* m1 = (unsigned*)(ed1 + NN * HEADS);
    float* den1 = (float*)(m1 + NN * HEADS);
    float* e2s  = den1 + NN * HEADS;               // N
    float* e2d  = e2s + NN;
    unsigned* m2 = (unsigned*)(e2d + NN);
    float* den2 = (float*)(m2 + NN);
    int* srcC   = (int*)(den2 + NN);               // E
    int* dstC   = srcC + EE;                       // E
    int* flag   = dstC + EE;                       // 1
    // aliases into h region (h dead after epass1_scatter)
    float* h2   = h;                               // N*40
    float* out2 = h + (long)NN * NCLASS;           // N*40

    hipMemsetAsync(flag, 0, 4, stream);
    hipMemsetAsync(out1, 0, (size_t)NN * F1 * 4, stream);

    detect_i64<<<16, 256, 0, stream>>>(ei, flag);
    canon_edges<<<(EE + 255) / 256, 256, 0, stream>>>(ei, flag, srcC, dstC);

    prep_w1<<<(NFEAT * F1 + 255) / 256, 256, 0, stream>>>(W1, w1th, w1tl);
    dim3 g1((NN + 63) / 64, F1 / 64);
    gemm1_kernel<<<g1, 256, 0, stream>>>(x, w1th, w1tl, h);
    escore1_kernel<<<(NN * HEADS) / 256, 256, 0, stream>>>(h, as1, ad1, es1, ed1, m1, den1);
    epass1_max<<<(int)(((long)ET * HEADS + 255) / 256), 256, 0, stream>>>(srcC, dstC, es1, ed1, m1);
    epass1_sum<<<(int)(((long)ET * HEADS + 255) / 256), 256, 0, stream>>>(srcC, dstC, es1, ed1, m1, den1);
    epass1_scatter<<<(ET + 3) / 4, 256, 0, stream>>>(srcC, dstC, es1, ed1, m1, den1, h, out1);
    bias_elu1<<<(int)(((long)NN * F1 + 255) / 256), 256, 0, stream>>>(out1, b1, h1o);

    hipMemsetAsync(out2, 0, (size_t)NN * NCLASS * 4, stream);
    gemm2_kernel<<<(int)(((long)NN * NCLASS + 255) / 256), 256, 0, stream>>>(out1, W2, h2);
    escore2_kernel<<<(NN + 255) / 256, 256, 0, stream>>>(h2, as2, ad2, e2s, e2d, m2, den2);
    epass2_max<<<(ET + 255) / 256, 256, 0, stream>>>(srcC, dstC, e2s, e2d, m2);
    epass2_sum<<<(ET + 255) / 256, 256, 0, stream>>>(srcC, dstC, e2s, e2d, m2, den2);
    epass2_scatter<<<(ET + 3) / 4, 256, 0, stream>>>(srcC, dstC, e2s, e2d, m2, den2, h2, out2);
    logsm_kernel<<<(NN + 255) / 256, 256, 0, stream>>>(out2, b2, out0);
}

// Round 3
// 1393.743 us; speedup vs baseline: 3.6128x; 3.6128x over previous
//
#include <hip/hip_runtime.h>

#define NN 100000
#define EE 1000000
#define NFEAT 512
#define NHID 32
#define HEADS 8
#define F1 256               // HEADS*NHID
#define NCLASS 40
#define SLOPE 0.2f
#define NB1 98               // ceil(NN/1024) scan blocks

typedef __bf16 bf16x8 __attribute__((ext_vector_type(8)));
typedef float f32x4 __attribute__((ext_vector_type(4)));

union BF8 { unsigned short s[8]; bf16x8 v; uint4 u; };

__device__ __forceinline__ float bf2f(unsigned short u) {
    return __uint_as_float(((unsigned)u) << 16);
}
__device__ __forceinline__ unsigned short f2bf(float f) {
    unsigned x = __float_as_uint(f);
    unsigned r = (x + 0x7fffu + ((x >> 16) & 1u)) >> 16;
    return (unsigned short)r;
}
__device__ __forceinline__ void cvt2(float f, unsigned short& hi, unsigned short& lo) {
    hi = f2bf(f);
    lo = f2bf(f - bf2f(hi));
}
__device__ __forceinline__ float lrelu(float x) { return x > 0.f ? x : SLOPE * x; }

// ---------------- edge-index canonicalization (int32 vs int64 layout) --------
__global__ void detect_i64(const int* __restrict__ ei, int* __restrict__ flag) {
    int i = blockIdx.x * 256 + threadIdx.x;
    if (i < 4096) {
        if (ei[2 * i + 1] != 0) atomicOr(flag, 1);   // int64 LE high words are 0
    }
}
__global__ void canon_edges(const int* __restrict__ ei, const int* __restrict__ flag,
                            int* __restrict__ srcC, int* __restrict__ dstC) {
    int e = blockIdx.x * 256 + threadIdx.x;
    if (e >= EE) return;
    if (*flag) {               // int32 layout
        srcC[e] = ei[e];
        dstC[e] = ei[EE + e];
    } else {                   // int64 little-endian layout
        srcC[e] = ei[2 * e];
        dstC[e] = ei[2 * EE + 2 * e];
    }
}

// ---------------- CSR build: count, scan, fill ----------------
__global__ void count_deg(const int* __restrict__ dstC, int* __restrict__ deg) {
    int e = blockIdx.x * 256 + threadIdx.x;
    if (e < EE) atomicAdd(deg + dstC[e], 1);
}
__global__ void scan1(const int* __restrict__ deg, int* __restrict__ bsum) {
    __shared__ int s[256];
    int b = blockIdx.x, t = threadIdx.x;
    int base = b * 1024 + t * 4, sum = 0;
    #pragma unroll
    for (int j = 0; j < 4; j++) { int i = base + j; sum += (i < NN) ? deg[i] : 0; }
    s[t] = sum; __syncthreads();
    for (int off = 128; off > 0; off >>= 1) {
        if (t < off) s[t] += s[t + off];
        __syncthreads();
    }
    if (t == 0) bsum[b] = s[0];
}
__global__ void scan2(int* __restrict__ bsum, int* __restrict__ row_ptr) {
    if (threadIdx.x == 0 && blockIdx.x == 0) {
        int acc = 0;
        for (int i = 0; i < NB1; i++) { int v = bsum[i]; bsum[i] = acc; acc += v; }
        row_ptr[NN] = EE;
    }
}
__global__ void scan3(const int* __restrict__ deg, const int* __restrict__ bsum,
                      int* __restrict__ row_ptr, int* __restrict__ pos) {
    __shared__ int ts[256];
    int b = blockIdx.x, t = threadIdx.x;
    int base = b * 1024 + t * 4;
    int v[4], sum = 0;
    #pragma unroll
    for (int j = 0; j < 4; j++) { int i = base + j; v[j] = (i < NN) ? deg[i] : 0; sum += v[j]; }
    ts[t] = sum; __syncthreads();
    for (int off = 1; off < 256; off <<= 1) {
        int add = (t >= off) ? ts[t - off] : 0;
        __syncthreads();
        ts[t] += add;
        __syncthreads();
    }
    int prefix = bsum[b] + ts[t] - sum;          // exclusive prefix for this thread
    #pragma unroll
    for (int j = 0; j < 4; j++) {
        int i = base + j;
        if (i < NN) { row_ptr[i] = prefix; pos[i] = prefix; prefix += v[j]; }
    }
}
__global__ void fill_csr(const int* __restrict__ srcC, const int* __restrict__ dstC,
                         int* __restrict__ pos, int* __restrict__ eadj) {
    int e = blockIdx.x * 256 + threadIdx.x;
    if (e >= EE) return;
    int idx = atomicAdd(pos + dstC[e], 1);
    eadj[idx] = srcC[e];
}

// ---------------- W1 prep: fp32 [512,256] -> hi/lo bf16 transposed [256,512] --
__global__ void prep_w1(const float* __restrict__ w1,
                        unsigned short* __restrict__ w1th,
                        unsigned short* __restrict__ w1tl) {
    int t = blockIdx.x * 256 + threadIdx.x;
    if (t < NFEAT * F1) {
        int k = t / F1, n = t % F1;
        unsigned short hi, lo;
        cvt2(w1[t], hi, lo);
        w1th[n * NFEAT + k] = hi;
        w1tl[n * NFEAT + k] = lo;
    }
}

// ---------------- GEMM1: h[N,256] = x[N,512] @ W1, split-bf16 MFMA -----------
__global__ __launch_bounds__(256) void gemm1_kernel(
    const float* __restrict__ x, const unsigned short* __restrict__ w1th,
    const unsigned short* __restrict__ w1tl, float* __restrict__ h) {
    int tid = threadIdx.x;
    int wave = tid >> 6, lane = tid & 63;
    int quad = lane >> 4, r = lane & 15;
    int mBase = blockIdx.x * 64 + wave * 16;
    int nBase = blockIdx.y * 64;
    long arow = mBase + r; if (arow > NN - 1) arow = NN - 1;
    const float4* aptr = (const float4*)(x + arow * NFEAT) + quad * 2;
    const uint4* bh0 = (const uint4*)(w1th + (long)(nBase + 0 * 16 + r) * NFEAT) + quad;
    const uint4* bh1 = (const uint4*)(w1th + (long)(nBase + 1 * 16 + r) * NFEAT) + quad;
    const uint4* bh2 = (const uint4*)(w1th + (long)(nBase + 2 * 16 + r) * NFEAT) + quad;
    const uint4* bh3 = (const uint4*)(w1th + (long)(nBase + 3 * 16 + r) * NFEAT) + quad;
    const uint4* bl0 = (const uint4*)(w1tl + (long)(nBase + 0 * 16 + r) * NFEAT) + quad;
    const uint4* bl1 = (const uint4*)(w1tl + (long)(nBase + 1 * 16 + r) * NFEAT) + quad;
    const uint4* bl2 = (const uint4*)(w1tl + (long)(nBase + 2 * 16 + r) * NFEAT) + quad;
    const uint4* bl3 = (const uint4*)(w1tl + (long)(nBase + 3 * 16 + r) * NFEAT) + quad;

    f32x4 acc0 = {0.f,0.f,0.f,0.f}, acc1 = {0.f,0.f,0.f,0.f};
    f32x4 acc2 = {0.f,0.f,0.f,0.f}, acc3 = {0.f,0.f,0.f,0.f};

    #pragma unroll
    for (int k = 0; k < NFEAT / 32; k++) {
        float4 fa0 = aptr[k * 8];
        float4 fa1 = aptr[k * 8 + 1];
        float fa[8] = {fa0.x, fa0.y, fa0.z, fa0.w, fa1.x, fa1.y, fa1.z, fa1.w};
        BF8 ah, al;
        #pragma unroll
        for (int j = 0; j < 8; j++) {
            unsigned short hh, ll;
            cvt2(fa[j], hh, ll);
            ah.s[j] = hh; al.s[j] = ll;
        }
        BF8 h0, h1_, h2_, h3, l0, l1, l2, l3;
        h0.u = bh0[k * 4]; h1_.u = bh1[k * 4]; h2_.u = bh2[k * 4]; h3.u = bh3[k * 4];
        l0.u = bl0[k * 4]; l1.u = bl1[k * 4]; l2.u = bl2[k * 4]; l3.u = bl3[k * 4];
        acc0 = __builtin_amdgcn_mfma_f32_16x16x32_bf16(ah.v, h0.v, acc0, 0, 0, 0);
        acc0 = __builtin_amdgcn_mfma_f32_16x16x32_bf16(al.v, h0.v, acc0, 0, 0, 0);
        acc0 = __builtin_amdgcn_mfma_f32_16x16x32_bf16(ah.v, l0.v, acc0, 0, 0, 0);
        acc1 = __builtin_amdgcn_mfma_f32_16x16x32_bf16(ah.v, h1_.v, acc1, 0, 0, 0);
        acc1 = __builtin_amdgcn_mfma_f32_16x16x32_bf16(al.v, h1_.v, acc1, 0, 0, 0);
        acc1 = __builtin_amdgcn_mfma_f32_16x16x32_bf16(ah.v, l1.v, acc1, 0, 0, 0);
        acc2 = __builtin_amdgcn_mfma_f32_16x16x32_bf16(ah.v, h2_.v, acc2, 0, 0, 0);
        acc2 = __builtin_amdgcn_mfma_f32_16x16x32_bf16(al.v, h2_.v, acc2, 0, 0, 0);
        acc2 = __builtin_amdgcn_mfma_f32_16x16x32_bf16(ah.v, l2.v, acc2, 0, 0, 0);
        acc3 = __builtin_amdgcn_mfma_f32_16x16x32_bf16(ah.v, h3.v, acc3, 0, 0, 0);
        acc3 = __builtin_amdgcn_mfma_f32_16x16x32_bf16(al.v, h3.v, acc3, 0, 0, 0);
        acc3 = __builtin_amdgcn_mfma_f32_16x16x32_bf16(ah.v, l3.v, acc3, 0, 0, 0);
    }
    #pragma unroll
    for (int i = 0; i < 4; i++) {
        int m = mBase + quad * 4 + i;
        if (m < NN) {
            float* hp = h + (long)m * F1 + nBase + r;
            hp[0]  = acc0[i];
            hp[16] = acc1[i];
            hp[32] = acc2[i];
            hp[48] = acc3[i];
        }
    }
}

// ---------------- e_src/e_dst layer1 ----------------
__global__ __launch_bounds__(256) void escore1_kernel(
    const float* __restrict__ h, const float* __restrict__ a_src,
    const float* __restrict__ a_dst, float* __restrict__ es, float* __restrict__ ed) {
    __shared__ float As[F1], Ad[F1];
    int tid = threadIdx.x;
    As[tid] = a_src[tid];
    Ad[tid] = a_dst[tid];
    __syncthreads();
    int t = blockIdx.x * 256 + tid;
    if (t >= NN * HEADS) return;
    int n = t >> 3, hd = t & 7;
    const float* hp = h + (long)n * F1 + hd * NHID;
    float s = 0.f, d = 0.f;
    #pragma unroll
    for (int c = 0; c < NHID; c++) {
        float v = hp[c];
        s += v * As[hd * NHID + c];
        d += v * Ad[hd * NHID + c];
    }
    es[t] = s; ed[t] = d;
}

// ---------------- layer-1 fused: softmax + aggregate + bias + ELU ------------
// one wave per dst node; lane covers 4 cols (float4); head = lane>>3
__global__ __launch_bounds__(256) void gat1_fused(
    const int* __restrict__ row_ptr, const int* __restrict__ eadj,
    const float* __restrict__ es, const float* __restrict__ ed,
    const float* __restrict__ h, const float* __restrict__ b1,
    float* __restrict__ h1o) {
    int wave = threadIdx.x >> 6, lane = threadIdx.x & 63;
    int d = blockIdx.x * 4 + wave;
    if (d >= NN) return;
    int hd = lane >> 3;
    float edv = ed[d * 8 + hd];
    int beg = row_ptr[d], end = row_ptr[d + 1];

    // pass A: per-head max (self-loop included)
    float mself = lrelu(es[d * 8 + hd] + edv);
    float m = mself;
    for (int i = beg; i < end; i += 64) {
        int myid = (i + lane < end) ? eadj[i + lane] : 0;
        int cnt = min(64, end - i);
        for (int j = 0; j < cnt; j++) {
            int s = __shfl(myid, j);
            m = fmaxf(m, lrelu(es[s * 8 + hd] + edv));
        }
    }
    // pass B: accumulate den and weighted sum
    float den = __expf(mself - m);
    float4 hv = ((const float4*)(h + (long)d * F1))[lane];
    float ax = den * hv.x, ay = den * hv.y, az = den * hv.z, aw = den * hv.w;
    for (int i = beg; i < end; i += 64) {
        int myid = (i + lane < end) ? eadj[i + lane] : 0;
        int cnt = min(64, end - i);
        for (int j = 0; j < cnt; j++) {
            int s = __shfl(myid, j);
            float w = __expf(lrelu(es[s * 8 + hd] + edv) - m);
            den += w;
            float4 v = ((const float4*)(h + (long)s * F1))[lane];
            ax += w * v.x; ay += w * v.y; az += w * v.z; aw += w * v.w;
        }
    }
    float4 bb = ((const float4*)b1)[lane];
    float inv = 1.f / den;
    float rx = ax * inv + bb.x, ry = ay * inv + bb.y,
          rz = az * inv + bb.z, rw = aw * inv + bb.w;
    rx = rx > 0.f ? rx : expm1f(rx);
    ry = ry > 0.f ? ry : expm1f(ry);
    rz = rz > 0.f ? rz : expm1f(rz);
    rw = rw > 0.f ? rw : expm1f(rw);
    float4 r = {rx, ry, rz, rw};
    ((float4*)(h1o + (long)d * F1))[lane] = r;
}

// ---------------- GEMM2: h2[N,40] = h1[N,256] @ W2 (fp32, W2 in LDS) ----------
__global__ __launch_bounds__(256) void gemm2_kernel(const float* __restrict__ h1,
                                                    const float* __restrict__ w2,
                                                    float* __restrict__ h2) {
    __shared__ float Ws[F1 * NCLASS];
    for (int i = threadIdx.x; i < F1 * NCLASS; i += 256) Ws[i] = w2[i];
    __syncthreads();
    long t = (long)blockIdx.x * 256 + threadIdx.x;
    if (t >= (long)NN * NCLASS) return;
    int n = (int)(t / NCLASS);
    int c = (int)(t - (long)n * NCLASS);
    const float* hp = h1 + (long)n * F1;
    float acc = 0.f;
    #pragma unroll 8
    for (int k = 0; k < F1; k++) acc += hp[k] * Ws[k * NCLASS + c];
    h2[t] = acc;
}

// ---------------- e_src/e_dst layer2 ----------------
__global__ void escore2_kernel(const float* __restrict__ h2,
                               const float* __restrict__ a_src2,
                               const float* __restrict__ a_dst2,
                               float* __restrict__ e2s, float* __restrict__ e2d) {
    __shared__ float As[NCLASS], Ad[NCLASS];
    if (threadIdx.x < NCLASS) {
        As[threadIdx.x] = a_src2[threadIdx.x];
        Ad[threadIdx.x] = a_dst2[threadIdx.x];
    }
    __syncthreads();
    int n = blockIdx.x * 256 + threadIdx.x;
    if (n >= NN) return;
    const float* hp = h2 + (long)n * NCLASS;
    float s = 0.f, d = 0.f;
    #pragma unroll
    for (int c = 0; c < NCLASS; c++) {
        float v = hp[c];
        s += v * As[c];
        d += v * Ad[c];
    }
    e2s[n] = s; e2d[n] = d;
}

// ---------------- layer-2 fused: softmax-agg + bias + log_softmax ------------
// one wave per dst node; lanes 0..39 hold classes
__global__ __launch_bounds__(256) void gat2_logsm(
    const int* __restrict__ row_ptr, const int* __restrict__ eadj,
    const float* __restrict__ e2s, const float* __restrict__ e2d,
    const float* __restrict__ h2, const float* __restrict__ b2,
    float* __restrict__ out0) {
    int wave = threadIdx.x >> 6, lane = threadIdx.x & 63;
    int d = blockIdx.x * 4 + wave;
    if (d >= NN) return;
    float edv = e2d[d];
    int beg = row_ptr[d], end = row_ptr[d + 1];

    float mself = lrelu(e2s[d] + edv);
    float m = mself;
    for (int i = beg; i < end; i += 64) {
        int myid = (i + lane < end) ? eadj[i + lane] : 0;
        int cnt = min(64, end - i);
        for (int j = 0; j < cnt; j++) {
            int s = __shfl(myid, j);
            m = fmaxf(m, lrelu(e2s[s] + edv));
        }
    }
    float den = __expf(mself - m);
    float acc = (lane < NCLASS) ? den * h2[(long)d * NCLASS + lane] : 0.f;
    for (int i = beg; i < end; i += 64) {
        int myid = (i + lane < end) ? eadj[i + lane] : 0;
        int cnt = min(64, end - i);
        for (int j = 0; j < cnt; j++) {
            int s = __shfl(myid, j);
            float w = __expf(lrelu(e2s[s] + edv) - m);
            den += w;
            if (lane < NCLASS) acc += w * h2[(long)s * NCLASS + lane];
        }
    }
    float v = (lane < NCLASS) ? acc / den + b2[lane] : -1e30f;
    float mx = v;
    #pragma unroll
    for (int off = 32; off; off >>= 1) mx = fmaxf(mx, __shfl_xor(mx, off));
    float ex = (lane < NCLASS) ? __expf(v - mx) : 0.f;
    float sm = ex;
    #pragma unroll
    for (int off = 32; off; off >>= 1) sm += __shfl_xor(sm, off);
    float ls = mx + logf(sm);
    if (lane < NCLASS) out0[(long)d * NCLASS + lane] = v - ls;
}

extern "C" void kernel_launch(void* const* d_in, const int* in_sizes, int n_in,
                              void* d_out, int out_size, void* d_ws, size_t ws_size,
                              hipStream_t stream) {
    const float* x   = (const float*)d_in[0];
    const int* ei    = (const int*)d_in[1];
    const float* W1  = (const float*)d_in[2];
    const float* as1 = (const float*)d_in[3];
    const float* ad1 = (const float*)d_in[4];
    const float* b1  = (const float*)d_in[5];
    const float* W2  = (const float*)d_in[6];
    const float* as2 = (const float*)d_in[7];
    const float* ad2 = (const float*)d_in[8];
    const float* b2  = (const float*)d_in[9];

    float* out0 = (float*)d_out;                   // [N,40] log_softmax
    float* h1o  = out0 + (long)NN * NCLASS;        // [N,256] h1 (fp32)

    // workspace layout
    float* h    = (float*)d_ws;                               // N*F1 fp32 (102.4 MB)
    unsigned short* w1th = (unsigned short*)(h + (long)NN * F1);   // 512*256 bf16
    unsigned short* w1tl = w1th + NFEAT * F1;
    float* es1  = (float*)(w1tl + NFEAT * F1);                // N*8
    float* ed1  = es1 + NN * HEADS;
    float* e2s  = ed1 + NN * HEADS;                           // N
    float* e2d  = e2s + NN;
    int* srcC   = (int*)(e2d + NN);                           // E
    int* dstC   = srcC + EE;                                  // E
    int* eadj   = dstC + EE;                                  // E
    int* deg    = eadj + EE;                                  // N
    int* row_ptr= deg + NN;                                   // N+1
    int* pos    = row_ptr + NN + 1;                           // N
    int* bsum   = pos + NN;                                   // NB1
    int* flag   = bsum + NB1;                                 // 1
    float* h2   = h;                                          // alias: N*40 (h dead after gat1)

    hipMemsetAsync(flag, 0, 4, stream);
    hipMemsetAsync(deg, 0, (size_t)NN * 4, stream);

    // edge canonicalization + CSR build
    detect_i64<<<16, 256, 0, stream>>>(ei, flag);
    canon_edges<<<(EE + 255) / 256, 256, 0, stream>>>(ei, flag, srcC, dstC);
    count_deg<<<(EE + 255) / 256, 256, 0, stream>>>(dstC, deg);
    scan1<<<NB1, 256, 0, stream>>>(deg, bsum);
    scan2<<<1, 64, 0, stream>>>(bsum, row_ptr);
    scan3<<<NB1, 256, 0, stream>>>(deg, bsum, row_ptr, pos);
    fill_csr<<<(EE + 255) / 256, 256, 0, stream>>>(srcC, dstC, pos, eadj);

    // layer 1
    prep_w1<<<(NFEAT * F1 + 255) / 256, 256, 0, stream>>>(W1, w1th, w1tl);
    dim3 g1((NN + 63) / 64, F1 / 64);
    gemm1_kernel<<<g1, 256, 0, stream>>>(x, w1th, w1tl, h);
    escore1_kernel<<<(NN * HEADS) / 256, 256, 0, stream>>>(h, as1, ad1, es1, ed1);
    gat1_fused<<<(NN + 3) / 4, 256, 0, stream>>>(row_ptr, eadj, es1, ed1, h, b1, h1o);

    // layer 2
    gemm2_kernel<<<(int)(((long)NN * NCLASS + 255) / 256), 256, 0, stream>>>(h1o, W2, h2);
    escore2_kernel<<<(NN + 255) / 256, 256, 0, stream>>>(h2, as2, ad2, e2s, e2d);
    gat2_logsm<<<(NN + 3) / 4, 256, 0, stream>>>(row_ptr, eadj, e2s, e2d, h2, b2, out0);
}